// Round 10
// baseline (614.727 us; speedup 1.0000x reference)
//
#include <hip/hip_runtime.h>

using f32x4 = __attribute__((ext_vector_type(4))) float;
using s16x8 = __attribute__((ext_vector_type(8))) short;
using u32x2 = __attribute__((ext_vector_type(2))) unsigned int;

static __device__ __forceinline__ unsigned short f2bf(float f) {
    union { float f; unsigned u; } v; v.f = f;
    unsigned r = v.u + 0x7fffu + ((v.u >> 16) & 1u);  // round-to-nearest-even
    return (unsigned short)(r >> 16);
}
static __device__ __forceinline__ float bf2f(unsigned short h) {
    union { unsigned u; float f; } v; v.u = ((unsigned)h) << 16;
    return v.f;
}

// ==================== pass 1: bin edges into 256 dst-range buckets ====================

__global__ __launch_bounds__(256) void partition_edges256(
        const int* __restrict__ src, const int* __restrict__ dst,
        int2* __restrict__ qpair, int* __restrict__ qcnt,
        int E, int span2, int qcap) {
    __shared__ int2 buf[256][32];
    __shared__ int cnt[256];
    const int tid = threadIdx.x;
    cnt[tid] = 0;
    __syncthreads();

    const int e0 = blockIdx.x * 2048;
    const int e1 = min(e0 + 2048, E);
    for (int i = e0 + tid; i < e1; i += 256) {
        int d = __builtin_nontemporal_load(&dst[i]);
        int s = __builtin_nontemporal_load(&src[i]);
        int b = (unsigned)d / (unsigned)span2;
        int p = atomicAdd(&cnt[b], 1);
        if (p < 32) {
            buf[b][p] = make_int2(d, s);
        } else {  // statistically-negligible overflow: direct global append
            int gp = atomicAdd(&qcnt[b], 1);
            qpair[(size_t)b * qcap + gp] = make_int2(d, s);
        }
    }
    __syncthreads();
    int c = min(cnt[tid], 32);
    if (c > 0) {
        int gb = atomicAdd(&qcnt[tid], c);
        int2* q = qpair + (size_t)tid * qcap + gb;
        for (int j = 0; j < c; ++j) {
            int2 p = buf[tid][j];
            __builtin_nontemporal_store(*(u32x2*)&p, (u32x2*)&q[j]);
        }
    }
}

// ==================== pass 2a: per-bucket LDS histogram -> deg ====================

__global__ __launch_bounds__(1024) void hist_bucket(
        const int2* __restrict__ qpair, const int* __restrict__ qcnt,
        int* __restrict__ deg, int N, int span2, int qcap) {
    __shared__ int h[512];
    const int b = blockIdx.x;
    const int base = b * span2;
    for (int k = threadIdx.x; k < span2; k += 1024) h[k] = 0;
    __syncthreads();
    const int len = qcnt[b];
    const int2* q = qpair + (size_t)b * qcap;
    for (int i = threadIdx.x; i < len; i += 1024) {
        u32x2 p = __builtin_nontemporal_load((const u32x2*)&q[i]);
        atomicAdd(&h[(int)p[0] - base], 1);
    }
    __syncthreads();
    int width = N - base; if (width > span2) width = span2; if (width < 0) width = 0;
    for (int k = threadIdx.x; k < width; k += 1024) deg[base + k] = h[k];
}

// ==================== exclusive scan (3-kernel); dinv fused into pass 1 ====================

__global__ void scan_blocks(const int* __restrict__ deg, int* __restrict__ excl,
                            int* __restrict__ block_sums, float* __restrict__ dinv, int n) {
    __shared__ int s[256];
    int t = threadIdx.x;
    int gid = blockIdx.x * 256 + t;
    int v = (gid < n) ? deg[gid] : 0;
    if (gid < n) dinv[gid] = rsqrtf((float)(v + 1));  // +1 self-loop
    s[t] = v;
    __syncthreads();
    #pragma unroll
    for (int off = 1; off < 256; off <<= 1) {
        int add = (t >= off) ? s[t - off] : 0;
        __syncthreads();
        s[t] += add;
        __syncthreads();
    }
    if (gid < n) excl[gid] = s[t] - v;
    if (t == 255) block_sums[blockIdx.x] = s[255];
}

__global__ void scan_sums(int* __restrict__ block_sums, int nb) {
    __shared__ int s[512];
    int t = threadIdx.x;
    int v = (t < nb) ? block_sums[t] : 0;
    s[t] = v;
    __syncthreads();
    #pragma unroll
    for (int off = 1; off < 512; off <<= 1) {
        int add = (t >= off) ? s[t - off] : 0;
        __syncthreads();
        s[t] += add;
        __syncthreads();
    }
    if (t < nb) block_sums[t] = s[t] - v;
}

__global__ void scan_add(int* __restrict__ excl, const int* __restrict__ block_sums,
                         int n, int E) {
    int gid = blockIdx.x * 256 + threadIdx.x;
    if (gid < n) excl[gid] += block_sums[gid >> 8];
    if (gid == n) excl[n] = E;
}

// ==================== pass 2b: per-bucket LDS-ranked placement ====================

__global__ __launch_bounds__(1024) void place_bucket(
        const int2* __restrict__ qpair, const int* __restrict__ qcnt,
        const int* __restrict__ rp, int* __restrict__ sorted_src,
        int N, int span2, int qcap) {
    __shared__ int cur[512];
    const int b = blockIdx.x;
    const int base = b * span2;
    for (int k = threadIdx.x; k < span2; k += 1024) {
        int idx = base + k;
        cur[k] = (idx < N) ? rp[idx] : 0;
    }
    __syncthreads();
    const int len = qcnt[b];
    const int2* q = qpair + (size_t)b * qcap;
    for (int i = threadIdx.x; i < len; i += 1024) {
        u32x2 p = __builtin_nontemporal_load((const u32x2*)&q[i]);
        int pos = atomicAdd(&cur[(int)p[0] - base], 1);
        sorted_src[pos] = (int)p[1];
    }
}

// ==================== weight conversion (single dispatch) ====================

__global__ void convert_weights(const float* __restrict__ W1, const float* __restrict__ W2,
                                unsigned short* __restrict__ W1b, unsigned short* __restrict__ W2b,
                                int n1_4, int n2_4) {
    int i = blockIdx.x * blockDim.x + threadIdx.x;
    int total = n1_4 + n2_4;
    int stride = gridDim.x * blockDim.x;
    for (; i < total; i += stride) {
        const float* in; unsigned short* o; int j;
        if (i < n1_4) { in = W1; o = W1b; j = i; } else { in = W2; o = W2b; j = i - n1_4; }
        float4 v = *(const float4*)&in[(size_t)j * 4];
        *(ushort4*)&o[(size_t)j * 4] = make_ushort4(f2bf(v.x), f2bf(v.y), f2bf(v.z), f2bf(v.w));
    }
}

// ==================== bf16 MFMA GEMM, full-width output tile ====================

template<int BN, bool AF32>
__global__ __launch_bounds__(256) void gemm_mfma(
        const void* __restrict__ Av, const unsigned short* __restrict__ B,
        unsigned short* __restrict__ C, const float* __restrict__ dinv,
        int M, int K) {
    constexpr int FN = BN / 64;
    __shared__ __align__(16) short As[64][40];   // pad 32->40
    __shared__ __align__(16) short Bt[BN][40];   // B transposed [col][k]

    const int tid  = threadIdx.x;
    const int lane = tid & 63;
    const int wave = tid >> 6;
    const int brow = blockIdx.x * 64;

    const int fr = lane & 15;
    const int kk = (lane >> 4) * 8;

    const int ar = tid >> 2;
    const int ac = (tid & 3) * 8;
    const int bk = tid >> 3;
    const int bc = (tid & 7) * (BN / 8);

    f32x4 acc[4][FN] = {};

    for (int k0 = 0; k0 < K; k0 += 32) {
        {
            int gr = brow + ar;
            s16x8 s = {};
            if (gr < M) {
                if constexpr (AF32) {
                    const float* A = (const float*)Av;
                    float4 v0 = *(const float4*)&A[(size_t)gr * K + k0 + ac];
                    float4 v1 = *(const float4*)&A[(size_t)gr * K + k0 + ac + 4];
                    s[0] = (short)f2bf(v0.x); s[1] = (short)f2bf(v0.y);
                    s[2] = (short)f2bf(v0.z); s[3] = (short)f2bf(v0.w);
                    s[4] = (short)f2bf(v1.x); s[5] = (short)f2bf(v1.y);
                    s[6] = (short)f2bf(v1.z); s[7] = (short)f2bf(v1.w);
                } else {
                    const unsigned short* A = (const unsigned short*)Av;
                    s = *(const s16x8*)&A[(size_t)gr * K + k0 + ac];
                }
            }
            *(s16x8*)&As[ar][ac] = s;
        }
        #pragma unroll
        for (int j2 = 0; j2 < BN / 64; ++j2) {
            s16x8 v = *(const s16x8*)&B[(size_t)(k0 + bk) * BN + bc + j2 * 8];
            #pragma unroll
            for (int j = 0; j < 8; ++j) Bt[bc + j2 * 8 + j][bk] = v[j];
        }
        __syncthreads();

        s16x8 af[4], bv[FN];
        #pragma unroll
        for (int fm = 0; fm < 4; ++fm)
            af[fm] = *(const s16x8*)&As[fm * 16 + fr][kk];
        #pragma unroll
        for (int fn = 0; fn < FN; ++fn)
            bv[fn] = *(const s16x8*)&Bt[wave * (BN / 4) + fn * 16 + fr][kk];
        #pragma unroll
        for (int fm = 0; fm < 4; ++fm)
            #pragma unroll
            for (int fn = 0; fn < FN; ++fn)
                acc[fm][fn] = __builtin_amdgcn_mfma_f32_16x16x32_bf16(
                    af[fm], bv[fn], acc[fm][fn], 0, 0, 0);
        __syncthreads();
    }

    // C/D layout: col = lane&15, row = (lane>>4)*4 + reg  [m89-verified]
    const int orow = (lane >> 4) * 4;
    #pragma unroll
    for (int fm = 0; fm < 4; ++fm) {
        #pragma unroll
        for (int reg = 0; reg < 4; ++reg) {
            int gr = brow + fm * 16 + orow + reg;
            if (gr < M) {
                float dv = dinv[gr];
                #pragma unroll
                for (int fn = 0; fn < FN; ++fn) {
                    int gc = wave * (BN / 4) + fn * 16 + fr;
                    __builtin_nontemporal_store(f2bf(dv * acc[fm][fn][reg]),
                                                &C[(size_t)gr * BN + gc]);
                }
            }
        }
    }
}

// ==================== pull aggregation (exclusive row_ptr) ====================
// NT: sorted_src stream loads, output stream stores. Gather loads stay cached.

__global__ __launch_bounds__(256) void agg_pull_256_bf16(
        const int* __restrict__ rp, const int* __restrict__ sorted_src,
        const float* __restrict__ dinv, const unsigned short* __restrict__ Hs,
        const float* __restrict__ bias, unsigned short* __restrict__ outb, int N) {
    int node = blockIdx.x * 4 + (threadIdx.x >> 6);
    int lane = threadIdx.x & 63;
    if (node >= N) return;

    int r0 = rp[node];
    int r1 = rp[node + 1];
    int c = lane << 2;
    ushort4 hv = *(const ushort4*)&Hs[(size_t)node * 256 + c];
    float a0 = bf2f(hv.x), a1 = bf2f(hv.y), a2 = bf2f(hv.z), a3 = bf2f(hv.w);

    int i = r0;
    for (; i + 8 <= r1; i += 8) {
        int s[8];
        #pragma unroll
        for (int u = 0; u < 8; ++u) s[u] = __builtin_nontemporal_load(&sorted_src[i + u]);
        ushort4 h[8];
        #pragma unroll
        for (int u = 0; u < 8; ++u) h[u] = *(const ushort4*)&Hs[(size_t)s[u] * 256 + c];
        #pragma unroll
        for (int u = 0; u < 8; ++u) {
            a0 += bf2f(h[u].x); a1 += bf2f(h[u].y);
            a2 += bf2f(h[u].z); a3 += bf2f(h[u].w);
        }
    }
    if (i + 4 <= r1) {
        int s[4];
        #pragma unroll
        for (int u = 0; u < 4; ++u) s[u] = __builtin_nontemporal_load(&sorted_src[i + u]);
        ushort4 h[4];
        #pragma unroll
        for (int u = 0; u < 4; ++u) h[u] = *(const ushort4*)&Hs[(size_t)s[u] * 256 + c];
        #pragma unroll
        for (int u = 0; u < 4; ++u) {
            a0 += bf2f(h[u].x); a1 += bf2f(h[u].y);
            a2 += bf2f(h[u].z); a3 += bf2f(h[u].w);
        }
        i += 4;
    }
    for (; i < r1; ++i) {
        ushort4 h = *(const ushort4*)&Hs[(size_t)sorted_src[i] * 256 + c];
        a0 += bf2f(h.x); a1 += bf2f(h.y); a2 += bf2f(h.z); a3 += bf2f(h.w);
    }

    float dv = dinv[node];
    float4 bb = *(const float4*)&bias[c];
    ushort4 o = make_ushort4(f2bf(fmaxf(bb.x + dv * a0, 0.f)),
                             f2bf(fmaxf(bb.y + dv * a1, 0.f)),
                             f2bf(fmaxf(bb.z + dv * a2, 0.f)),
                             f2bf(fmaxf(bb.w + dv * a3, 0.f)));
    __builtin_nontemporal_store(*(u32x2*)&o, (u32x2*)&outb[(size_t)node * 256 + c]);
}

__global__ __launch_bounds__(256) void agg_pull_128_bf16(
        const int* __restrict__ rp, const int* __restrict__ sorted_src,
        const float* __restrict__ dinv, const unsigned short* __restrict__ Hs,
        const float* __restrict__ bias, float* __restrict__ out, int N) {
    int node = blockIdx.x * 4 + (threadIdx.x >> 6);
    int lane = threadIdx.x & 63;
    if (node >= N) return;

    int r0 = rp[node];
    int r1 = rp[node + 1];
    int c = lane << 1;
    ushort2 hv = *(const ushort2*)&Hs[(size_t)node * 128 + c];
    float a0 = bf2f(hv.x), a1 = bf2f(hv.y);

    int i = r0;
    for (; i + 8 <= r1; i += 8) {
        int s[8];
        #pragma unroll
        for (int u = 0; u < 8; ++u) s[u] = __builtin_nontemporal_load(&sorted_src[i + u]);
        ushort2 h[8];
        #pragma unroll
        for (int u = 0; u < 8; ++u) h[u] = *(const ushort2*)&Hs[(size_t)s[u] * 128 + c];
        #pragma unroll
        for (int u = 0; u < 8; ++u) { a0 += bf2f(h[u].x); a1 += bf2f(h[u].y); }
    }
    if (i + 4 <= r1) {
        int s[4];
        #pragma unroll
        for (int u = 0; u < 4; ++u) s[u] = __builtin_nontemporal_load(&sorted_src[i + u]);
        ushort2 h[4];
        #pragma unroll
        for (int u = 0; u < 4; ++u) h[u] = *(const ushort2*)&Hs[(size_t)s[u] * 128 + c];
        #pragma unroll
        for (int u = 0; u < 4; ++u) { a0 += bf2f(h[u].x); a1 += bf2f(h[u].y); }
        i += 4;
    }
    for (; i < r1; ++i) {
        ushort2 h = *(const ushort2*)&Hs[(size_t)sorted_src[i] * 128 + c];
        a0 += bf2f(h.x); a1 += bf2f(h.y);
    }

    float dv = dinv[node];
    float2 bb = *(const float2*)&bias[c];
    float2 o = make_float2(bb.x + dv * a0, bb.y + dv * a1);
    __builtin_nontemporal_store(o.x, &out[(size_t)node * 128 + c]);
    __builtin_nontemporal_store(o.y, &out[(size_t)node * 128 + c + 1]);
}

// ==================== launch ====================

extern "C" void kernel_launch(void* const* d_in, const int* in_sizes, int n_in,
                              void* d_out, int out_size, void* d_ws, size_t ws_size,
                              hipStream_t stream) {
    const float* x   = (const float*)d_in[0];
    const int*   ei  = (const int*)d_in[1];
    const float* W1  = (const float*)d_in[2];
    const float* b1  = (const float*)d_in[3];
    const float* W2  = (const float*)d_in[4];
    const float* b2  = (const float*)d_in[5];
    float* out       = (float*)d_out;

    const int E   = in_sizes[1] / 2;           // 3,200,000
    const int HID = in_sizes[3];               // 256
    const int IN  = in_sizes[2] / HID;         // 256
    const int OUT = in_sizes[5];               // 128
    const int N   = in_sizes[0] / IN;          // 100,000
    const int span2 = (N + 255) / 256;         // 391 (dst-range per bucket, <=512)
    const int qcap  = E / 256 + 1536;          // bucket capacity w/ ~12-sigma slack

    char* ws = (char*)d_ws;
    int*   row_ptr    = (int*)ws;                                     // (N+1) ints
    int*   deg        = (int*)(ws + (512 << 10));                     // N ints
    float* dinv       = (float*)(ws + (1 << 20));                     // N floats
    int*   block_sums = (int*)(ws + 1572864);                         // ~400 ints
    int*   qcnt       = (int*)(ws + 1638400);                         // 256 ints
    unsigned short* W1b = (unsigned short*)(ws + 1703936);            // 256*256 bf16
    unsigned short* W2b = (unsigned short*)(ws + 1867776);            // 256*128 bf16
    int*   sorted_src = (int*)(ws + (2 << 20));                       // E ints (12.8MB)
    unsigned short* Hsb = (unsigned short*)(ws + ((size_t)16 << 20)); // N*256 bf16 (51.2MB)
    unsigned short* A1b = (unsigned short*)(ws + ((size_t)80 << 20)); // N*256 bf16 (51.2MB)
    int2*  qpair      = (int2*)(ws + ((size_t)136 << 20));            // 256*qcap int2 (~28.5MB)

    const int* e_src = ei;
    const int* e_dst = ei + E;
    const int nb_scan = (N + 255) / 256;

    // ---- CSR build: bin -> hist -> scan -> place (no global atomic ranking) ----
    hipMemsetAsync(qcnt, 0, 256 * sizeof(int), stream);
    partition_edges256<<<(E + 2047) / 2048, 256, 0, stream>>>(e_src, e_dst, qpair, qcnt,
                                                              E, span2, qcap);
    hist_bucket<<<256, 1024, 0, stream>>>(qpair, qcnt, deg, N, span2, qcap);
    scan_blocks<<<nb_scan, 256, 0, stream>>>(deg, row_ptr, block_sums, dinv, N);
    scan_sums<<<1, 512, 0, stream>>>(block_sums, nb_scan);
    scan_add<<<(N + 256) / 256, 256, 0, stream>>>(row_ptr, block_sums, N, E);
    place_bucket<<<256, 1024, 0, stream>>>(qpair, qcnt, row_ptr, sorted_src, N, span2, qcap);

    // ---- weight conversions (one dispatch) ----
    convert_weights<<<48, 256, 0, stream>>>(W1, W2, W1b, W2b, IN * HID / 4, HID * OUT / 4);

    // ---- layer 1: Hsb = bf16(dinv * (X@W1)), X read as f32 ----
    gemm_mfma<256, true><<<(N + 63) / 64, 256, 0, stream>>>(x, W1b, Hsb, dinv, N, IN);
    agg_pull_256_bf16<<<(N + 3) / 4, 256, 0, stream>>>(row_ptr, sorted_src, dinv, Hsb, b1, A1b, N);

    // ---- layer 2: Hs2 = bf16(dinv * (A1b@W2)) (reuses Hsb region) ----
    gemm_mfma<128, false><<<(N + 63) / 64, 256, 0, stream>>>(A1b, W2b, Hsb, dinv, N, HID);
    agg_pull_128_bf16<<<(N + 3) / 4, 256, 0, stream>>>(row_ptr, sorted_src, dinv, Hsb, b2, out, N);
}

// Round 11
// 536.680 us; speedup vs baseline: 1.1454x; 1.1454x over previous
//
#include <hip/hip_runtime.h>

using f32x4 = __attribute__((ext_vector_type(4))) float;
using s16x8 = __attribute__((ext_vector_type(8))) short;

static __device__ __forceinline__ unsigned short f2bf(float f) {
    union { float f; unsigned u; } v; v.f = f;
    unsigned r = v.u + 0x7fffu + ((v.u >> 16) & 1u);  // round-to-nearest-even
    return (unsigned short)(r >> 16);
}
static __device__ __forceinline__ float bf2f(unsigned short h) {
    union { unsigned u; float f; } v; v.u = ((unsigned)h) << 16;
    return v.f;
}

// ==================== pass 1: bin edges into 256 dst-range buckets ====================

__global__ __launch_bounds__(256) void partition_edges256(
        const int* __restrict__ src, const int* __restrict__ dst,
        int2* __restrict__ qpair, int* __restrict__ qcnt,
        int E, int span2, int qcap) {
    __shared__ int2 buf[256][32];
    __shared__ int cnt[256];
    const int tid = threadIdx.x;
    cnt[tid] = 0;
    __syncthreads();

    const int e0 = blockIdx.x * 2048;
    const int e1 = min(e0 + 2048, E);
    for (int i = e0 + tid; i < e1; i += 256) {
        int d = dst[i];
        int s = src[i];
        int b = (unsigned)d / (unsigned)span2;
        int p = atomicAdd(&cnt[b], 1);
        if (p < 32) {
            buf[b][p] = make_int2(d, s);
        } else {  // statistically-negligible overflow: direct global append
            int gp = atomicAdd(&qcnt[b], 1);
            qpair[(size_t)b * qcap + gp] = make_int2(d, s);
        }
    }
    __syncthreads();
    int c = min(cnt[tid], 32);
    if (c > 0) {
        int gb = atomicAdd(&qcnt[tid], c);
        int2* q = qpair + (size_t)tid * qcap + gb;
        for (int j = 0; j < c; ++j) q[j] = buf[tid][j];
    }
}

// ==================== pass 2a: per-bucket LDS histogram -> deg ====================

__global__ __launch_bounds__(1024) void hist_bucket(
        const int2* __restrict__ qpair, const int* __restrict__ qcnt,
        int* __restrict__ deg, int N, int span2, int qcap) {
    __shared__ int h[512];
    const int b = blockIdx.x;
    const int base = b * span2;
    for (int k = threadIdx.x; k < span2; k += 1024) h[k] = 0;
    __syncthreads();
    const int len = qcnt[b];
    const int2* q = qpair + (size_t)b * qcap;
    for (int i = threadIdx.x; i < len; i += 1024)
        atomicAdd(&h[q[i].x - base], 1);
    __syncthreads();
    int width = N - base; if (width > span2) width = span2; if (width < 0) width = 0;
    for (int k = threadIdx.x; k < width; k += 1024) deg[base + k] = h[k];
}

// ==================== exclusive scan (3-kernel); dinv fused into pass 1 ====================

__global__ void scan_blocks(const int* __restrict__ deg, int* __restrict__ excl,
                            int* __restrict__ block_sums, float* __restrict__ dinv, int n) {
    __shared__ int s[256];
    int t = threadIdx.x;
    int gid = blockIdx.x * 256 + t;
    int v = (gid < n) ? deg[gid] : 0;
    if (gid < n) dinv[gid] = rsqrtf((float)(v + 1));  // +1 self-loop
    s[t] = v;
    __syncthreads();
    #pragma unroll
    for (int off = 1; off < 256; off <<= 1) {
        int add = (t >= off) ? s[t - off] : 0;
        __syncthreads();
        s[t] += add;
        __syncthreads();
    }
    if (gid < n) excl[gid] = s[t] - v;
    if (t == 255) block_sums[blockIdx.x] = s[255];
}

__global__ void scan_sums(int* __restrict__ block_sums, int nb) {
    __shared__ int s[512];
    int t = threadIdx.x;
    int v = (t < nb) ? block_sums[t] : 0;
    s[t] = v;
    __syncthreads();
    #pragma unroll
    for (int off = 1; off < 512; off <<= 1) {
        int add = (t >= off) ? s[t - off] : 0;
        __syncthreads();
        s[t] += add;
        __syncthreads();
    }
    if (t < nb) block_sums[t] = s[t] - v;
}

__global__ void scan_add(int* __restrict__ excl, const int* __restrict__ block_sums,
                         int n, int E) {
    int gid = blockIdx.x * 256 + threadIdx.x;
    if (gid < n) excl[gid] += block_sums[gid >> 8];
    if (gid == n) excl[n] = E;
}

// ==================== pass 2b: per-bucket LDS-ranked placement ====================

__global__ __launch_bounds__(1024) void place_bucket(
        const int2* __restrict__ qpair, const int* __restrict__ qcnt,
        const int* __restrict__ rp, int* __restrict__ sorted_src,
        int N, int span2, int qcap) {
    __shared__ int cur[512];
    const int b = blockIdx.x;
    const int base = b * span2;
    for (int k = threadIdx.x; k < span2; k += 1024) {
        int idx = base + k;
        cur[k] = (idx < N) ? rp[idx] : 0;
    }
    __syncthreads();
    const int len = qcnt[b];
    const int2* q = qpair + (size_t)b * qcap;
    for (int i = threadIdx.x; i < len; i += 1024) {
        int2 p = q[i];
        int pos = atomicAdd(&cur[p.x - base], 1);
        sorted_src[pos] = p.y;
    }
}

// ==================== weight conversion (single dispatch) ====================

__global__ void convert_weights(const float* __restrict__ W1, const float* __restrict__ W2,
                                unsigned short* __restrict__ W1b, unsigned short* __restrict__ W2b,
                                int n1_4, int n2_4) {
    int i = blockIdx.x * blockDim.x + threadIdx.x;
    int total = n1_4 + n2_4;
    int stride = gridDim.x * blockDim.x;
    for (; i < total; i += stride) {
        const float* in; unsigned short* o; int j;
        if (i < n1_4) { in = W1; o = W1b; j = i; } else { in = W2; o = W2b; j = i - n1_4; }
        float4 v = *(const float4*)&in[(size_t)j * 4];
        *(ushort4*)&o[(size_t)j * 4] = make_ushort4(f2bf(v.x), f2bf(v.y), f2bf(v.z), f2bf(v.w));
    }
}

// ==================== bf16 MFMA GEMM, full-width output tile ====================

template<int BN, bool AF32>
__global__ __launch_bounds__(256) void gemm_mfma(
        const void* __restrict__ Av, const unsigned short* __restrict__ B,
        unsigned short* __restrict__ C, const float* __restrict__ dinv,
        int M, int K) {
    constexpr int FN = BN / 64;
    __shared__ __align__(16) short As[64][40];   // pad 32->40
    __shared__ __align__(16) short Bt[BN][40];   // B transposed [col][k]

    const int tid  = threadIdx.x;
    const int lane = tid & 63;
    const int wave = tid >> 6;
    const int brow = blockIdx.x * 64;

    const int fr = lane & 15;
    const int kk = (lane >> 4) * 8;

    const int ar = tid >> 2;
    const int ac = (tid & 3) * 8;
    const int bk = tid >> 3;
    const int bc = (tid & 7) * (BN / 8);

    f32x4 acc[4][FN] = {};

    for (int k0 = 0; k0 < K; k0 += 32) {
        {
            int gr = brow + ar;
            s16x8 s = {};
            if (gr < M) {
                if constexpr (AF32) {
                    const float* A = (const float*)Av;
                    float4 v0 = *(const float4*)&A[(size_t)gr * K + k0 + ac];
                    float4 v1 = *(const float4*)&A[(size_t)gr * K + k0 + ac + 4];
                    s[0] = (short)f2bf(v0.x); s[1] = (short)f2bf(v0.y);
                    s[2] = (short)f2bf(v0.z); s[3] = (short)f2bf(v0.w);
                    s[4] = (short)f2bf(v1.x); s[5] = (short)f2bf(v1.y);
                    s[6] = (short)f2bf(v1.z); s[7] = (short)f2bf(v1.w);
                } else {
                    const unsigned short* A = (const unsigned short*)Av;
                    s = *(const s16x8*)&A[(size_t)gr * K + k0 + ac];
                }
            }
            *(s16x8*)&As[ar][ac] = s;
        }
        #pragma unroll
        for (int j2 = 0; j2 < BN / 64; ++j2) {
            s16x8 v = *(const s16x8*)&B[(size_t)(k0 + bk) * BN + bc + j2 * 8];
            #pragma unroll
            for (int j = 0; j < 8; ++j) Bt[bc + j2 * 8 + j][bk] = v[j];
        }
        __syncthreads();

        s16x8 af[4], bv[FN];
        #pragma unroll
        for (int fm = 0; fm < 4; ++fm)
            af[fm] = *(const s16x8*)&As[fm * 16 + fr][kk];
        #pragma unroll
        for (int fn = 0; fn < FN; ++fn)
            bv[fn] = *(const s16x8*)&Bt[wave * (BN / 4) + fn * 16 + fr][kk];
        #pragma unroll
        for (int fm = 0; fm < 4; ++fm)
            #pragma unroll
            for (int fn = 0; fn < FN; ++fn)
                acc[fm][fn] = __builtin_amdgcn_mfma_f32_16x16x32_bf16(
                    af[fm], bv[fn], acc[fm][fn], 0, 0, 0);
        __syncthreads();
    }

    // C/D layout: col = lane&15, row = (lane>>4)*4 + reg  [m89-verified]
    const int orow = (lane >> 4) * 4;
    #pragma unroll
    for (int fm = 0; fm < 4; ++fm) {
        #pragma unroll
        for (int reg = 0; reg < 4; ++reg) {
            int gr = brow + fm * 16 + orow + reg;
            if (gr < M) {
                float dv = dinv[gr];
                #pragma unroll
                for (int fn = 0; fn < FN; ++fn) {
                    int gc = wave * (BN / 4) + fn * 16 + fr;
                    C[(size_t)gr * BN + gc] = f2bf(dv * acc[fm][fn][reg]);
                }
            }
        }
    }
}

// ==================== pull aggregation ====================

__global__ __launch_bounds__(256) void agg_pull_256_bf16(
        const int* __restrict__ rp, const int* __restrict__ sorted_src,
        const float* __restrict__ dinv, const unsigned short* __restrict__ Hs,
        const float* __restrict__ bias, unsigned short* __restrict__ outb, int N) {
    int node = blockIdx.x * 4 + (threadIdx.x >> 6);
    int lane = threadIdx.x & 63;
    if (node >= N) return;

    int r0 = rp[node];
    int r1 = rp[node + 1];
    int c = lane << 2;
    ushort4 hv = *(const ushort4*)&Hs[(size_t)node * 256 + c];
    float a0 = bf2f(hv.x), a1 = bf2f(hv.y), a2 = bf2f(hv.z), a3 = bf2f(hv.w);

    int i = r0;
    for (; i + 8 <= r1; i += 8) {
        int s[8];
        #pragma unroll
        for (int u = 0; u < 8; ++u) s[u] = sorted_src[i + u];
        ushort4 h[8];
        #pragma unroll
        for (int u = 0; u < 8; ++u) h[u] = *(const ushort4*)&Hs[(size_t)s[u] * 256 + c];
        #pragma unroll
        for (int u = 0; u < 8; ++u) {
            a0 += bf2f(h[u].x); a1 += bf2f(h[u].y);
            a2 += bf2f(h[u].z); a3 += bf2f(h[u].w);
        }
    }
    if (i + 4 <= r1) {
        int s[4];
        #pragma unroll
        for (int u = 0; u < 4; ++u) s[u] = sorted_src[i + u];
        ushort4 h[4];
        #pragma unroll
        for (int u = 0; u < 4; ++u) h[u] = *(const ushort4*)&Hs[(size_t)s[u] * 256 + c];
        #pragma unroll
        for (int u = 0; u < 4; ++u) {
            a0 += bf2f(h[u].x); a1 += bf2f(h[u].y);
            a2 += bf2f(h[u].z); a3 += bf2f(h[u].w);
        }
        i += 4;
    }
    for (; i < r1; ++i) {
        ushort4 h = *(const ushort4*)&Hs[(size_t)sorted_src[i] * 256 + c];
        a0 += bf2f(h.x); a1 += bf2f(h.y); a2 += bf2f(h.z); a3 += bf2f(h.w);
    }

    float dv = dinv[node];
    float4 bb = *(const float4*)&bias[c];
    float o0 = fmaxf(bb.x + dv * a0, 0.f);
    float o1 = fmaxf(bb.y + dv * a1, 0.f);
    float o2 = fmaxf(bb.z + dv * a2, 0.f);
    float o3 = fmaxf(bb.w + dv * a3, 0.f);
    *(ushort4*)&outb[(size_t)node * 256 + c] = make_ushort4(f2bf(o0), f2bf(o1), f2bf(o2), f2bf(o3));
}

// layer-2 agg: 2 nodes per wave (32 lanes/node, ushort4 = 8B loads per lane)

__global__ __launch_bounds__(256) void agg_pull_128_bf16(
        const int* __restrict__ rp, const int* __restrict__ sorted_src,
        const float* __restrict__ dinv, const unsigned short* __restrict__ Hs,
        const float* __restrict__ bias, float* __restrict__ out, int N) {
    int node = blockIdx.x * 8 + ((threadIdx.x >> 6) << 1) + ((threadIdx.x >> 5) & 1);
    int l = threadIdx.x & 31;
    if (node >= N) return;

    int r0 = rp[node];
    int r1 = rp[node + 1];
    int c = l << 2;
    ushort4 hv = *(const ushort4*)&Hs[(size_t)node * 128 + c];
    float a0 = bf2f(hv.x), a1 = bf2f(hv.y), a2 = bf2f(hv.z), a3 = bf2f(hv.w);

    int i = r0;
    for (; i + 8 <= r1; i += 8) {
        int s[8];
        #pragma unroll
        for (int u = 0; u < 8; ++u) s[u] = sorted_src[i + u];
        ushort4 h[8];
        #pragma unroll
        for (int u = 0; u < 8; ++u) h[u] = *(const ushort4*)&Hs[(size_t)s[u] * 128 + c];
        #pragma unroll
        for (int u = 0; u < 8; ++u) {
            a0 += bf2f(h[u].x); a1 += bf2f(h[u].y);
            a2 += bf2f(h[u].z); a3 += bf2f(h[u].w);
        }
    }
    if (i + 4 <= r1) {
        int s[4];
        #pragma unroll
        for (int u = 0; u < 4; ++u) s[u] = sorted_src[i + u];
        ushort4 h[4];
        #pragma unroll
        for (int u = 0; u < 4; ++u) h[u] = *(const ushort4*)&Hs[(size_t)s[u] * 128 + c];
        #pragma unroll
        for (int u = 0; u < 4; ++u) {
            a0 += bf2f(h[u].x); a1 += bf2f(h[u].y);
            a2 += bf2f(h[u].z); a3 += bf2f(h[u].w);
        }
        i += 4;
    }
    for (; i < r1; ++i) {
        ushort4 h = *(const ushort4*)&Hs[(size_t)sorted_src[i] * 128 + c];
        a0 += bf2f(h.x); a1 += bf2f(h.y); a2 += bf2f(h.z); a3 += bf2f(h.w);
    }

    float dv = dinv[node];
    float4 bb = *(const float4*)&bias[c];
    float4 o = make_float4(bb.x + dv * a0, bb.y + dv * a1,
                           bb.z + dv * a2, bb.w + dv * a3);
    *(float4*)&out[(size_t)node * 128 + c] = o;
}

// ==================== launch ====================

extern "C" void kernel_launch(void* const* d_in, const int* in_sizes, int n_in,
                              void* d_out, int out_size, void* d_ws, size_t ws_size,
                              hipStream_t stream) {
    const float* x   = (const float*)d_in[0];
    const int*   ei  = (const int*)d_in[1];
    const float* W1  = (const float*)d_in[2];
    const float* b1  = (const float*)d_in[3];
    const float* W2  = (const float*)d_in[4];
    const float* b2  = (const float*)d_in[5];
    float* out       = (float*)d_out;

    const int E   = in_sizes[1] / 2;           // 3,200,000
    const int HID = in_sizes[3];               // 256
    const int IN  = in_sizes[2] / HID;         // 256
    const int OUT = in_sizes[5];               // 128
    const int N   = in_sizes[0] / IN;          // 100,000
    const int span2 = (N + 255) / 256;         // 391 (dst-range per bucket, <=512)
    const int qcap  = E / 256 + 1536;          // bucket capacity w/ ~12-sigma slack

    char* ws = (char*)d_ws;
    int*   row_ptr    = (int*)ws;                                     // (N+1) ints
    int*   deg        = (int*)(ws + (512 << 10));                     // N ints
    float* dinv       = (float*)(ws + (1 << 20));                     // N floats
    int*   block_sums = (int*)(ws + 1572864);                         // ~400 ints
    int*   qcnt       = (int*)(ws + 1638400);                         // 256 ints
    unsigned short* W1b = (unsigned short*)(ws + 1703936);            // 256*256 bf16
    unsigned short* W2b = (unsigned short*)(ws + 1867776);            // 256*128 bf16
    int*   sorted_src = (int*)(ws + (2 << 20));                       // E ints (12.8MB)
    unsigned short* Hsb = (unsigned short*)(ws + ((size_t)16 << 20)); // N*256 bf16 (51.2MB)
    unsigned short* A1b = (unsigned short*)(ws + ((size_t)80 << 20)); // N*256 bf16 (51.2MB)
    int2*  qpair      = (int2*)(ws + ((size_t)136 << 20));            // 256*qcap int2 (~28.5MB)

    const int* e_src = ei;
    const int* e_dst = ei + E;
    const int nb_scan = (N + 255) / 256;

    // ---- CSR build: bin -> hist -> scan -> place (no global atomic ranking) ----
    hipMemsetAsync(qcnt, 0, 256 * sizeof(int), stream);
    partition_edges256<<<(E + 2047) / 2048, 256, 0, stream>>>(e_src, e_dst, qpair, qcnt,
                                                              E, span2, qcap);
    hist_bucket<<<256, 1024, 0, stream>>>(qpair, qcnt, deg, N, span2, qcap);
    scan_blocks<<<nb_scan, 256, 0, stream>>>(deg, row_ptr, block_sums, dinv, N);
    scan_sums<<<1, 512, 0, stream>>>(block_sums, nb_scan);
    scan_add<<<(N + 256) / 256, 256, 0, stream>>>(row_ptr, block_sums, N, E);
    place_bucket<<<256, 1024, 0, stream>>>(qpair, qcnt, row_ptr, sorted_src, N, span2, qcap);

    // ---- weight conversions (one dispatch) ----
    convert_weights<<<48, 256, 0, stream>>>(W1, W2, W1b, W2b, IN * HID / 4, HID * OUT / 4);

    // ---- layer 1: Hsb = bf16(dinv * (X@W1)), X read as f32 ----
    gemm_mfma<256, true><<<(N + 63) / 64, 256, 0, stream>>>(x, W1b, Hsb, dinv, N, IN);
    agg_pull_256_bf16<<<(N + 3) / 4, 256, 0, stream>>>(row_ptr, sorted_src, dinv, Hsb, b1, A1b, N);

    // ---- layer 2: Hs2 = bf16(dinv * (A1b@W2)) (reuses Hsb region) ----
    gemm_mfma<128, false><<<(N + 63) / 64, 256, 0, stream>>>(A1b, W2b, Hsb, dinv, N, HID);
    agg_pull_128_bf16<<<(N + 7) / 8, 256, 0, stream>>>(row_ptr, sorted_src, dinv, Hsb, b2, out, N);
}

// Round 12
// 497.192 us; speedup vs baseline: 1.2364x; 1.0794x over previous
//
#include <hip/hip_runtime.h>

using f32x4 = __attribute__((ext_vector_type(4))) float;
using s16x8 = __attribute__((ext_vector_type(8))) short;

static __device__ __forceinline__ unsigned short f2bf(float f) {
    union { float f; unsigned u; } v; v.f = f;
    unsigned r = v.u + 0x7fffu + ((v.u >> 16) & 1u);  // round-to-nearest-even
    return (unsigned short)(r >> 16);
}
static __device__ __forceinline__ float bf2f(unsigned short h) {
    union { unsigned u; float f; } v; v.u = ((unsigned)h) << 16;
    return v.f;
}

// ==================== pass 1: bin edges into 256 dst-range buckets ====================

__global__ __launch_bounds__(256) void partition_edges256(
        const int* __restrict__ src, const int* __restrict__ dst,
        int2* __restrict__ qpair, int* __restrict__ qcnt,
        int E, int span2, int qcap) {
    __shared__ int2 buf[256][32];
    __shared__ int cnt[256];
    const int tid = threadIdx.x;
    cnt[tid] = 0;
    __syncthreads();

    const int e0 = blockIdx.x * 2048;
    const int e1 = min(e0 + 2048, E);
    for (int i = e0 + tid; i < e1; i += 256) {
        int d = dst[i];
        int s = src[i];
        int b = (unsigned)d / (unsigned)span2;
        int p = atomicAdd(&cnt[b], 1);
        if (p < 32) {
            buf[b][p] = make_int2(d, s);
        } else {  // statistically-negligible overflow: direct global append
            int gp = atomicAdd(&qcnt[b], 1);
            qpair[(size_t)b * qcap + gp] = make_int2(d, s);
        }
    }
    __syncthreads();
    int c = min(cnt[tid], 32);
    if (c > 0) {
        int gb = atomicAdd(&qcnt[tid], c);
        int2* q = qpair + (size_t)tid * qcap + gb;
        for (int j = 0; j < c; ++j) q[j] = buf[tid][j];
    }
}

// ==================== pass 2a: per-bucket LDS histogram -> deg ====================

__global__ __launch_bounds__(1024) void hist_bucket(
        const int2* __restrict__ qpair, const int* __restrict__ qcnt,
        int* __restrict__ deg, int N, int span2, int qcap) {
    __shared__ int h[512];
    const int b = blockIdx.x;
    const int base = b * span2;
    for (int k = threadIdx.x; k < span2; k += 1024) h[k] = 0;
    __syncthreads();
    const int len = qcnt[b];
    const int2* q = qpair + (size_t)b * qcap;
    for (int i = threadIdx.x; i < len; i += 1024)
        atomicAdd(&h[q[i].x - base], 1);
    __syncthreads();
    int width = N - base; if (width > span2) width = span2; if (width < 0) width = 0;
    for (int k = threadIdx.x; k < width; k += 1024) deg[base + k] = h[k];
}

// ==================== exclusive scan (3-kernel); dinv fused into pass 1 ====================

__global__ void scan_blocks(const int* __restrict__ deg, int* __restrict__ excl,
                            int* __restrict__ block_sums, float* __restrict__ dinv, int n) {
    __shared__ int s[256];
    int t = threadIdx.x;
    int gid = blockIdx.x * 256 + t;
    int v = (gid < n) ? deg[gid] : 0;
    if (gid < n) dinv[gid] = rsqrtf((float)(v + 1));  // +1 self-loop
    s[t] = v;
    __syncthreads();
    #pragma unroll
    for (int off = 1; off < 256; off <<= 1) {
        int add = (t >= off) ? s[t - off] : 0;
        __syncthreads();
        s[t] += add;
        __syncthreads();
    }
    if (gid < n) excl[gid] = s[t] - v;
    if (t == 255) block_sums[blockIdx.x] = s[255];
}

__global__ void scan_sums(int* __restrict__ block_sums, int nb) {
    __shared__ int s[512];
    int t = threadIdx.x;
    int v = (t < nb) ? block_sums[t] : 0;
    s[t] = v;
    __syncthreads();
    #pragma unroll
    for (int off = 1; off < 512; off <<= 1) {
        int add = (t >= off) ? s[t - off] : 0;
        __syncthreads();
        s[t] += add;
        __syncthreads();
    }
    if (t < nb) block_sums[t] = s[t] - v;
}

__global__ void scan_add(int* __restrict__ excl, const int* __restrict__ block_sums,
                         int n, int E) {
    int gid = blockIdx.x * 256 + threadIdx.x;
    if (gid < n) excl[gid] += block_sums[gid >> 8];
    if (gid == n) excl[n] = E;
}

// ==================== pass 2b: per-bucket LDS-ranked placement ====================

__global__ __launch_bounds__(1024) void place_bucket(
        const int2* __restrict__ qpair, const int* __restrict__ qcnt,
        const int* __restrict__ rp, int* __restrict__ sorted_src,
        int N, int span2, int qcap) {
    __shared__ int cur[512];
    const int b = blockIdx.x;
    const int base = b * span2;
    for (int k = threadIdx.x; k < span2; k += 1024) {
        int idx = base + k;
        cur[k] = (idx < N) ? rp[idx] : 0;
    }
    __syncthreads();
    const int len = qcnt[b];
    const int2* q = qpair + (size_t)b * qcap;
    for (int i = threadIdx.x; i < len; i += 1024) {
        int2 p = q[i];
        int pos = atomicAdd(&cur[p.x - base], 1);
        sorted_src[pos] = p.y;
    }
}

// ==================== weight convert + TRANSPOSE (single dispatch) ====================
// W1t[n][k] = bf16(W1[k][n]); W2t[n][k] = bf16(W2[k][n]). Tiny matrices; strided
// reads are fine (<=256KB).

__global__ void convert_weights_t(const float* __restrict__ W1, const float* __restrict__ W2,
                                  unsigned short* __restrict__ W1t, unsigned short* __restrict__ W2t,
                                  int K, int N1, int N2) {
    int i = blockIdx.x * blockDim.x + threadIdx.x;
    int k4 = K / 4;
    int tot1 = N1 * k4;
    int tot2 = N2 * k4;
    if (i < tot1) {
        int n = i / k4, k0 = (i % k4) * 4;
        ushort4 o = make_ushort4(f2bf(W1[(size_t)(k0 + 0) * N1 + n]),
                                 f2bf(W1[(size_t)(k0 + 1) * N1 + n]),
                                 f2bf(W1[(size_t)(k0 + 2) * N1 + n]),
                                 f2bf(W1[(size_t)(k0 + 3) * N1 + n]));
        *(ushort4*)&W1t[(size_t)n * K + k0] = o;
    } else if (i - tot1 < tot2) {
        int j = i - tot1;
        int n = j / k4, k0 = (j % k4) * 4;
        ushort4 o = make_ushort4(f2bf(W2[(size_t)(k0 + 0) * N2 + n]),
                                 f2bf(W2[(size_t)(k0 + 1) * N2 + n]),
                                 f2bf(W2[(size_t)(k0 + 2) * N2 + n]),
                                 f2bf(W2[(size_t)(k0 + 3) * N2 + n]));
        *(ushort4*)&W2t[(size_t)n * K + k0] = o;
    }
}

// ==================== bf16 MFMA GEMM, pre-transposed B ====================
// C[M][BN] = bf16( dinv[row] * (A@B) ); Bt_g is B pre-transposed: Bt_g[n][k].
// Tile 64 rows x BN, BK=32, 4 waves. B-stage is now a pure vector copy.

template<int BN, bool AF32>
__global__ __launch_bounds__(256) void gemm_mfma(
        const void* __restrict__ Av, const unsigned short* __restrict__ Bt_g,
        unsigned short* __restrict__ C, const float* __restrict__ dinv,
        int M, int K) {
    constexpr int FN = BN / 64;
    __shared__ __align__(16) short As[64][40];   // pad 32->40
    __shared__ __align__(16) short Bt[BN][40];   // [col][k], vector-filled

    const int tid  = threadIdx.x;
    const int lane = tid & 63;
    const int wave = tid >> 6;
    const int brow = blockIdx.x * 64;

    const int fr = lane & 15;
    const int kk = (lane >> 4) * 8;

    const int ar = tid >> 2;
    const int ac = (tid & 3) * 8;

    f32x4 acc[4][FN] = {};

    for (int k0 = 0; k0 < K; k0 += 32) {
        // ---- stage A (convert if f32) ----
        {
            int gr = brow + ar;
            s16x8 s = {};
            if (gr < M) {
                if constexpr (AF32) {
                    const float* A = (const float*)Av;
                    float4 v0 = *(const float4*)&A[(size_t)gr * K + k0 + ac];
                    float4 v1 = *(const float4*)&A[(size_t)gr * K + k0 + ac + 4];
                    s[0] = (short)f2bf(v0.x); s[1] = (short)f2bf(v0.y);
                    s[2] = (short)f2bf(v0.z); s[3] = (short)f2bf(v0.w);
                    s[4] = (short)f2bf(v1.x); s[5] = (short)f2bf(v1.y);
                    s[6] = (short)f2bf(v1.z); s[7] = (short)f2bf(v1.w);
                } else {
                    const unsigned short* A = (const unsigned short*)Av;
                    s = *(const s16x8*)&A[(size_t)gr * K + k0 + ac];
                }
            }
            *(s16x8*)&As[ar][ac] = s;
        }
        // ---- stage B: vector copy from pre-transposed weights ----
        // chunk ci covers (col = ci>>2, kc = (ci&3)*8); BN*4 chunks total.
        #pragma unroll
        for (int p = 0; p < BN / 64; ++p) {
            int ci = tid + p * 256;
            int col = ci >> 2;
            int kc = (ci & 3) * 8;
            s16x8 v = *(const s16x8*)&Bt_g[(size_t)col * K + k0 + kc];
            *(s16x8*)&Bt[col][kc] = v;
        }
        __syncthreads();

        s16x8 af[4], bv[FN];
        #pragma unroll
        for (int fm = 0; fm < 4; ++fm)
            af[fm] = *(const s16x8*)&As[fm * 16 + fr][kk];
        #pragma unroll
        for (int fn = 0; fn < FN; ++fn)
            bv[fn] = *(const s16x8*)&Bt[wave * (BN / 4) + fn * 16 + fr][kk];
        #pragma unroll
        for (int fm = 0; fm < 4; ++fm)
            #pragma unroll
            for (int fn = 0; fn < FN; ++fn)
                acc[fm][fn] = __builtin_amdgcn_mfma_f32_16x16x32_bf16(
                    af[fm], bv[fn], acc[fm][fn], 0, 0, 0);
        __syncthreads();
    }

    // C/D layout: col = lane&15, row = (lane>>4)*4 + reg  [m89-verified]
    const int orow = (lane >> 4) * 4;
    #pragma unroll
    for (int fm = 0; fm < 4; ++fm) {
        #pragma unroll
        for (int reg = 0; reg < 4; ++reg) {
            int gr = brow + fm * 16 + orow + reg;
            if (gr < M) {
                float dv = dinv[gr];
                #pragma unroll
                for (int fn = 0; fn < FN; ++fn) {
                    int gc = wave * (BN / 4) + fn * 16 + fr;
                    C[(size_t)gr * BN + gc] = f2bf(dv * acc[fm][fn][reg]);
                }
            }
        }
    }
}

// ==================== pull aggregation ====================

__global__ __launch_bounds__(256) void agg_pull_256_bf16(
        const int* __restrict__ rp, const int* __restrict__ sorted_src,
        const float* __restrict__ dinv, const unsigned short* __restrict__ Hs,
        const float* __restrict__ bias, unsigned short* __restrict__ outb, int N) {
    int node = blockIdx.x * 4 + (threadIdx.x >> 6);
    int lane = threadIdx.x & 63;
    if (node >= N) return;

    int r0 = rp[node];
    int r1 = rp[node + 1];
    int c = lane << 2;
    ushort4 hv = *(const ushort4*)&Hs[(size_t)node * 256 + c];
    float a0 = bf2f(hv.x), a1 = bf2f(hv.y), a2 = bf2f(hv.z), a3 = bf2f(hv.w);

    int i = r0;
    for (; i + 8 <= r1; i += 8) {
        int s[8];
        #pragma unroll
        for (int u = 0; u < 8; ++u) s[u] = sorted_src[i + u];
        ushort4 h[8];
        #pragma unroll
        for (int u = 0; u < 8; ++u) h[u] = *(const ushort4*)&Hs[(size_t)s[u] * 256 + c];
        #pragma unroll
        for (int u = 0; u < 8; ++u) {
            a0 += bf2f(h[u].x); a1 += bf2f(h[u].y);
            a2 += bf2f(h[u].z); a3 += bf2f(h[u].w);
        }
    }
    if (i + 4 <= r1) {
        int s[4];
        #pragma unroll
        for (int u = 0; u < 4; ++u) s[u] = sorted_src[i + u];
        ushort4 h[4];
        #pragma unroll
        for (int u = 0; u < 4; ++u) h[u] = *(const ushort4*)&Hs[(size_t)s[u] * 256 + c];
        #pragma unroll
        for (int u = 0; u < 4; ++u) {
            a0 += bf2f(h[u].x); a1 += bf2f(h[u].y);
            a2 += bf2f(h[u].z); a3 += bf2f(h[u].w);
        }
        i += 4;
    }
    for (; i < r1; ++i) {
        ushort4 h = *(const ushort4*)&Hs[(size_t)sorted_src[i] * 256 + c];
        a0 += bf2f(h.x); a1 += bf2f(h.y); a2 += bf2f(h.z); a3 += bf2f(h.w);
    }

    float dv = dinv[node];
    float4 bb = *(const float4*)&bias[c];
    float o0 = fmaxf(bb.x + dv * a0, 0.f);
    float o1 = fmaxf(bb.y + dv * a1, 0.f);
    float o2 = fmaxf(bb.z + dv * a2, 0.f);
    float o3 = fmaxf(bb.w + dv * a3, 0.f);
    *(ushort4*)&outb[(size_t)node * 256 + c] = make_ushort4(f2bf(o0), f2bf(o1), f2bf(o2), f2bf(o3));
}

// layer-2 agg: 2 nodes per wave (32 lanes/node, ushort4 = 8B loads per lane)

__global__ __launch_bounds__(256) void agg_pull_128_bf16(
        const int* __restrict__ rp, const int* __restrict__ sorted_src,
        const float* __restrict__ dinv, const unsigned short* __restrict__ Hs,
        const float* __restrict__ bias, float* __restrict__ out, int N) {
    int node = blockIdx.x * 8 + ((threadIdx.x >> 6) << 1) + ((threadIdx.x >> 5) & 1);
    int l = threadIdx.x & 31;
    if (node >= N) return;

    int r0 = rp[node];
    int r1 = rp[node + 1];
    int c = l << 2;
    ushort4 hv = *(const ushort4*)&Hs[(size_t)node * 128 + c];
    float a0 = bf2f(hv.x), a1 = bf2f(hv.y), a2 = bf2f(hv.z), a3 = bf2f(hv.w);

    int i = r0;
    for (; i + 8 <= r1; i += 8) {
        int s[8];
        #pragma unroll
        for (int u = 0; u < 8; ++u) s[u] = sorted_src[i + u];
        ushort4 h[8];
        #pragma unroll
        for (int u = 0; u < 8; ++u) h[u] = *(const ushort4*)&Hs[(size_t)s[u] * 128 + c];
        #pragma unroll
        for (int u = 0; u < 8; ++u) {
            a0 += bf2f(h[u].x); a1 += bf2f(h[u].y);
            a2 += bf2f(h[u].z); a3 += bf2f(h[u].w);
        }
    }
    if (i + 4 <= r1) {
        int s[4];
        #pragma unroll
        for (int u = 0; u < 4; ++u) s[u] = sorted_src[i + u];
        ushort4 h[4];
        #pragma unroll
        for (int u = 0; u < 4; ++u) h[u] = *(const ushort4*)&Hs[(size_t)s[u] * 128 + c];
        #pragma unroll
        for (int u = 0; u < 4; ++u) {
            a0 += bf2f(h[u].x); a1 += bf2f(h[u].y);
            a2 += bf2f(h[u].z); a3 += bf2f(h[u].w);
        }
        i += 4;
    }
    for (; i < r1; ++i) {
        ushort4 h = *(const ushort4*)&Hs[(size_t)sorted_src[i] * 128 + c];
        a0 += bf2f(h.x); a1 += bf2f(h.y); a2 += bf2f(h.z); a3 += bf2f(h.w);
    }

    float dv = dinv[node];
    float4 bb = *(const float4*)&bias[c];
    float4 o = make_float4(bb.x + dv * a0, bb.y + dv * a1,
                           bb.z + dv * a2, bb.w + dv * a3);
    *(float4*)&out[(size_t)node * 128 + c] = o;
}

// ==================== launch ====================

extern "C" void kernel_launch(void* const* d_in, const int* in_sizes, int n_in,
                              void* d_out, int out_size, void* d_ws, size_t ws_size,
                              hipStream_t stream) {
    const float* x   = (const float*)d_in[0];
    const int*   ei  = (const int*)d_in[1];
    const float* W1  = (const float*)d_in[2];
    const float* b1  = (const float*)d_in[3];
    const float* W2  = (const float*)d_in[4];
    const float* b2  = (const float*)d_in[5];
    float* out       = (float*)d_out;

    const int E   = in_sizes[1] / 2;           // 3,200,000
    const int HID = in_sizes[3];               // 256
    const int IN  = in_sizes[2] / HID;         // 256
    const int OUT = in_sizes[5];               // 128
    const int N   = in_sizes[0] / IN;          // 100,000
    const int span2 = (N + 255) / 256;         // 391 (dst-range per bucket, <=512)
    const int qcap  = E / 256 + 1536;          // bucket capacity w/ ~12-sigma slack

    char* ws = (char*)d_ws;
    int*   row_ptr    = (int*)ws;                                     // (N+1) ints
    int*   deg        = (int*)(ws + (512 << 10));                     // N ints
    float* dinv       = (float*)(ws + (1 << 20));                     // N floats
    int*   block_sums = (int*)(ws + 1572864);                         // ~400 ints
    int*   qcnt       = (int*)(ws + 1638400);                         // 256 ints
    unsigned short* W1t = (unsigned short*)(ws + 1703936);            // 256*256 bf16 (transposed)
    unsigned short* W2t = (unsigned short*)(ws + 1867776);            // 128*256 bf16 (transposed)
    int*   sorted_src = (int*)(ws + (2 << 20));                       // E ints (12.8MB)
    unsigned short* Hsb = (unsigned short*)(ws + ((size_t)16 << 20)); // N*256 bf16 (51.2MB)
    unsigned short* A1b = (unsigned short*)(ws + ((size_t)80 << 20)); // N*256 bf16 (51.2MB)
    int2*  qpair      = (int2*)(ws + ((size_t)136 << 20));            // 256*qcap int2 (~28.5MB)

    const int* e_src = ei;
    const int* e_dst = ei + E;
    const int nb_scan = (N + 255) / 256;

    // ---- CSR build: bin -> hist -> scan -> place (no global atomic ranking) ----
    hipMemsetAsync(qcnt, 0, 256 * sizeof(int), stream);
    partition_edges256<<<(E + 2047) / 2048, 256, 0, stream>>>(e_src, e_dst, qpair, qcnt,
                                                              E, span2, qcap);
    hist_bucket<<<256, 1024, 0, stream>>>(qpair, qcnt, deg, N, span2, qcap);
    scan_blocks<<<nb_scan, 256, 0, stream>>>(deg, row_ptr, block_sums, dinv, N);
    scan_sums<<<1, 512, 0, stream>>>(block_sums, nb_scan);
    scan_add<<<(N + 256) / 256, 256, 0, stream>>>(row_ptr, block_sums, N, E);
    place_bucket<<<256, 1024, 0, stream>>>(qpair, qcnt, row_ptr, sorted_src, N, span2, qcap);

    // ---- weight convert + transpose (one dispatch) ----
    convert_weights_t<<<96, 256, 0, stream>>>(W1, W2, W1t, W2t, IN, HID, OUT);

    // ---- layer 1: Hsb = bf16(dinv * (X@W1)), X read as f32 ----
    gemm_mfma<256, true><<<(N + 63) / 64, 256, 0, stream>>>(x, W1t, Hsb, dinv, N, IN);
    agg_pull_256_bf16<<<(N + 3) / 4, 256, 0, stream>>>(row_ptr, sorted_src, dinv, Hsb, b1, A1b, N);

    // ---- layer 2: Hs2 = bf16(dinv * (A1b@W2)) (reuses Hsb region) ----
    gemm_mfma<128, false><<<(N + 63) / 64, 256, 0, stream>>>(A1b, W2t, Hsb, dinv, N, HID);
    agg_pull_128_bf16<<<(N + 7) / 8, 256, 0, stream>>>(row_ptr, sorted_src, dinv, Hsb, b2, out, N);
}

// Round 13
// 485.709 us; speedup vs baseline: 1.2656x; 1.0236x over previous
//
#include <hip/hip_runtime.h>

using f32x4 = __attribute__((ext_vector_type(4))) float;
using s16x8 = __attribute__((ext_vector_type(8))) short;

static __device__ __forceinline__ unsigned short f2bf(float f) {
    union { float f; unsigned u; } v; v.f = f;
    unsigned r = v.u + 0x7fffu + ((v.u >> 16) & 1u);  // round-to-nearest-even
    return (unsigned short)(r >> 16);
}
static __device__ __forceinline__ float bf2f(unsigned short h) {
    union { unsigned u; float f; } v; v.u = ((unsigned)h) << 16;
    return v.f;
}

// ==================== pass 1: bin edges into 256 dst-range buckets ====================

__global__ __launch_bounds__(256) void partition_edges256(
        const int* __restrict__ src, const int* __restrict__ dst,
        int2* __restrict__ qpair, int* __restrict__ qcnt,
        int E, int span2, int qcap) {
    __shared__ int2 buf[256][32];
    __shared__ int cnt[256];
    const int tid = threadIdx.x;
    cnt[tid] = 0;
    __syncthreads();

    const int e0 = blockIdx.x * 2048;
    const int e1 = min(e0 + 2048, E);
    for (int i = e0 + tid; i < e1; i += 256) {
        int d = dst[i];
        int s = src[i];
        int b = (unsigned)d / (unsigned)span2;
        int p = atomicAdd(&cnt[b], 1);
        if (p < 32) {
            buf[b][p] = make_int2(d, s);
        } else {  // statistically-negligible overflow: direct global append
            int gp = atomicAdd(&qcnt[b], 1);
            qpair[(size_t)b * qcap + gp] = make_int2(d, s);
        }
    }
    __syncthreads();
    int c = min(cnt[tid], 32);
    if (c > 0) {
        int gb = atomicAdd(&qcnt[tid], c);
        int2* q = qpair + (size_t)tid * qcap + gb;
        for (int j = 0; j < c; ++j) q[j] = buf[tid][j];
    }
}

// ==================== pass 2a: per-bucket LDS histogram -> deg ====================

__global__ __launch_bounds__(1024) void hist_bucket(
        const int2* __restrict__ qpair, const int* __restrict__ qcnt,
        int* __restrict__ deg, int N, int span2, int qcap) {
    __shared__ int h[512];
    const int b = blockIdx.x;
    const int base = b * span2;
    for (int k = threadIdx.x; k < span2; k += 1024) h[k] = 0;
    __syncthreads();
    const int len = qcnt[b];
    const int2* q = qpair + (size_t)b * qcap;
    for (int i = threadIdx.x; i < len; i += 1024)
        atomicAdd(&h[q[i].x - base], 1);
    __syncthreads();
    int width = N - base; if (width > span2) width = span2; if (width < 0) width = 0;
    for (int k = threadIdx.x; k < width; k += 1024) deg[base + k] = h[k];
}

// ==================== exclusive scan (3-kernel); dinv fused into pass 1 ====================

__global__ void scan_blocks(const int* __restrict__ deg, int* __restrict__ excl,
                            int* __restrict__ block_sums, float* __restrict__ dinv, int n) {
    __shared__ int s[256];
    int t = threadIdx.x;
    int gid = blockIdx.x * 256 + t;
    int v = (gid < n) ? deg[gid] : 0;
    if (gid < n) dinv[gid] = rsqrtf((float)(v + 1));  // +1 self-loop
    s[t] = v;
    __syncthreads();
    #pragma unroll
    for (int off = 1; off < 256; off <<= 1) {
        int add = (t >= off) ? s[t - off] : 0;
        __syncthreads();
        s[t] += add;
        __syncthreads();
    }
    if (gid < n) excl[gid] = s[t] - v;
    if (t == 255) block_sums[blockIdx.x] = s[255];
}

__global__ void scan_sums(int* __restrict__ block_sums, int nb) {
    __shared__ int s[512];
    int t = threadIdx.x;
    int v = (t < nb) ? block_sums[t] : 0;
    s[t] = v;
    __syncthreads();
    #pragma unroll
    for (int off = 1; off < 512; off <<= 1) {
        int add = (t >= off) ? s[t - off] : 0;
        __syncthreads();
        s[t] += add;
        __syncthreads();
    }
    if (t < nb) block_sums[t] = s[t] - v;
}

__global__ void scan_add(int* __restrict__ excl, const int* __restrict__ block_sums,
                         int n, int E) {
    int gid = blockIdx.x * 256 + threadIdx.x;
    if (gid < n) excl[gid] += block_sums[gid >> 8];
    if (gid == n) excl[n] = E;
}

// ==================== pass 2b: per-bucket LDS-ranked placement ====================

__global__ __launch_bounds__(1024) void place_bucket(
        const int2* __restrict__ qpair, const int* __restrict__ qcnt,
        const int* __restrict__ rp, int* __restrict__ sorted_src,
        int N, int span2, int qcap) {
    __shared__ int cur[512];
    const int b = blockIdx.x;
    const int base = b * span2;
    for (int k = threadIdx.x; k < span2; k += 1024) {
        int idx = base + k;
        cur[k] = (idx < N) ? rp[idx] : 0;
    }
    __syncthreads();
    const int len = qcnt[b];
    const int2* q = qpair + (size_t)b * qcap;
    for (int i = threadIdx.x; i < len; i += 1024) {
        int2 p = q[i];
        int pos = atomicAdd(&cur[p.x - base], 1);
        sorted_src[pos] = p.y;
    }
}

// ==================== weight convert + TRANSPOSE (single dispatch) ====================

__global__ void convert_weights_t(const float* __restrict__ W1, const float* __restrict__ W2,
                                  unsigned short* __restrict__ W1t, unsigned short* __restrict__ W2t,
                                  int K, int N1, int N2) {
    int i = blockIdx.x * blockDim.x + threadIdx.x;
    int k4 = K / 4;
    int tot1 = N1 * k4;
    int tot2 = N2 * k4;
    if (i < tot1) {
        int n = i / k4, k0 = (i % k4) * 4;
        ushort4 o = make_ushort4(f2bf(W1[(size_t)(k0 + 0) * N1 + n]),
                                 f2bf(W1[(size_t)(k0 + 1) * N1 + n]),
                                 f2bf(W1[(size_t)(k0 + 2) * N1 + n]),
                                 f2bf(W1[(size_t)(k0 + 3) * N1 + n]));
        *(ushort4*)&W1t[(size_t)n * K + k0] = o;
    } else if (i - tot1 < tot2) {
        int j = i - tot1;
        int n = j / k4, k0 = (j % k4) * 4;
        ushort4 o = make_ushort4(f2bf(W2[(size_t)(k0 + 0) * N2 + n]),
                                 f2bf(W2[(size_t)(k0 + 1) * N2 + n]),
                                 f2bf(W2[(size_t)(k0 + 2) * N2 + n]),
                                 f2bf(W2[(size_t)(k0 + 3) * N2 + n]));
        *(ushort4*)&W2t[(size_t)n * K + k0] = o;
    }
}

// ==================== bf16 MFMA GEMM, 128-row tile, 8 waves ====================
// C[M][BN] = bf16( dinv[row] * (A@B) ); Bt_g pre-transposed [n][k].
// 512 threads = 8 waves in 2x4 grid: wave (wm,wn) owns rows wm*64+64, cols wn*(BN/4).
// 128 MFMAs per barrier-pair (BN=256), one-pass A-stage.

template<int BN, bool AF32>
__global__ __launch_bounds__(512) void gemm_mfma(
        const void* __restrict__ Av, const unsigned short* __restrict__ Bt_g,
        unsigned short* __restrict__ C, const float* __restrict__ dinv,
        int M, int K) {
    constexpr int FN = BN / 64;                  // n-fragments per wave (4 or 2)
    __shared__ __align__(16) short As[128][40];  // pad 32->40
    __shared__ __align__(16) short Bt[BN][40];   // [col][k], vector-filled

    const int tid  = threadIdx.x;
    const int lane = tid & 63;
    const int wave = tid >> 6;                   // 0..7
    const int wm = wave >> 2;                    // 0..1 (row half)
    const int wn = wave & 3;                     // 0..3 (col quarter)
    const int brow = blockIdx.x * 128;

    const int fr = lane & 15;
    const int kk = (lane >> 4) * 8;

    const int ar = tid >> 2;                     // 0..127
    const int ac = (tid & 3) * 8;                // 0,8,16,24

    f32x4 acc[4][FN] = {};

    for (int k0 = 0; k0 < K; k0 += 32) {
        // ---- stage A: one pass, 512 x s16x8 ----
        {
            int gr = brow + ar;
            s16x8 s = {};
            if (gr < M) {
                if constexpr (AF32) {
                    const float* A = (const float*)Av;
                    float4 v0 = *(const float4*)&A[(size_t)gr * K + k0 + ac];
                    float4 v1 = *(const float4*)&A[(size_t)gr * K + k0 + ac + 4];
                    s[0] = (short)f2bf(v0.x); s[1] = (short)f2bf(v0.y);
                    s[2] = (short)f2bf(v0.z); s[3] = (short)f2bf(v0.w);
                    s[4] = (short)f2bf(v1.x); s[5] = (short)f2bf(v1.y);
                    s[6] = (short)f2bf(v1.z); s[7] = (short)f2bf(v1.w);
                } else {
                    const unsigned short* A = (const unsigned short*)Av;
                    s = *(const s16x8*)&A[(size_t)gr * K + k0 + ac];
                }
            }
            *(s16x8*)&As[ar][ac] = s;
        }
        // ---- stage B: vector copy from pre-transposed weights ----
        #pragma unroll
        for (int p = 0; p < BN / 128; ++p) {     // BN=256: 2 passes; BN=128: 1
            int ci = tid + p * 512;
            int col = ci >> 2;
            int kc = (ci & 3) * 8;
            s16x8 v = *(const s16x8*)&Bt_g[(size_t)col * K + k0 + kc];
            *(s16x8*)&Bt[col][kc] = v;
        }
        __syncthreads();

        s16x8 af[4], bv[FN];
        #pragma unroll
        for (int fm = 0; fm < 4; ++fm)
            af[fm] = *(const s16x8*)&As[wm * 64 + fm * 16 + fr][kk];
        #pragma unroll
        for (int fn = 0; fn < FN; ++fn)
            bv[fn] = *(const s16x8*)&Bt[wn * (BN / 4) + fn * 16 + fr][kk];
        #pragma unroll
        for (int fm = 0; fm < 4; ++fm)
            #pragma unroll
            for (int fn = 0; fn < FN; ++fn)
                acc[fm][fn] = __builtin_amdgcn_mfma_f32_16x16x32_bf16(
                    af[fm], bv[fn], acc[fm][fn], 0, 0, 0);
        __syncthreads();
    }

    // C/D layout: col = lane&15, row = (lane>>4)*4 + reg  [m89-verified]
    const int orow = (lane >> 4) * 4;
    #pragma unroll
    for (int fm = 0; fm < 4; ++fm) {
        #pragma unroll
        for (int reg = 0; reg < 4; ++reg) {
            int gr = brow + wm * 64 + fm * 16 + orow + reg;
            if (gr < M) {
                float dv = dinv[gr];
                #pragma unroll
                for (int fn = 0; fn < FN; ++fn) {
                    int gc = wn * (BN / 4) + fn * 16 + fr;
                    C[(size_t)gr * BN + gc] = f2bf(dv * acc[fm][fn][reg]);
                }
            }
        }
    }
}

// ==================== pull aggregation ====================

__global__ __launch_bounds__(256) void agg_pull_256_bf16(
        const int* __restrict__ rp, const int* __restrict__ sorted_src,
        const float* __restrict__ dinv, const unsigned short* __restrict__ Hs,
        const float* __restrict__ bias, unsigned short* __restrict__ outb, int N) {
    int node = blockIdx.x * 4 + (threadIdx.x >> 6);
    int lane = threadIdx.x & 63;
    if (node >= N) return;

    int r0 = rp[node];
    int r1 = rp[node + 1];
    int c = lane << 2;
    ushort4 hv = *(const ushort4*)&Hs[(size_t)node * 256 + c];
    float a0 = bf2f(hv.x), a1 = bf2f(hv.y), a2 = bf2f(hv.z), a3 = bf2f(hv.w);

    int i = r0;
    for (; i + 8 <= r1; i += 8) {
        int s[8];
        #pragma unroll
        for (int u = 0; u < 8; ++u) s[u] = sorted_src[i + u];
        ushort4 h[8];
        #pragma unroll
        for (int u = 0; u < 8; ++u) h[u] = *(const ushort4*)&Hs[(size_t)s[u] * 256 + c];
        #pragma unroll
        for (int u = 0; u < 8; ++u) {
            a0 += bf2f(h[u].x); a1 += bf2f(h[u].y);
            a2 += bf2f(h[u].z); a3 += bf2f(h[u].w);
        }
    }
    if (i + 4 <= r1) {
        int s[4];
        #pragma unroll
        for (int u = 0; u < 4; ++u) s[u] = sorted_src[i + u];
        ushort4 h[4];
        #pragma unroll
        for (int u = 0; u < 4; ++u) h[u] = *(const ushort4*)&Hs[(size_t)s[u] * 256 + c];
        #pragma unroll
        for (int u = 0; u < 4; ++u) {
            a0 += bf2f(h[u].x); a1 += bf2f(h[u].y);
            a2 += bf2f(h[u].z); a3 += bf2f(h[u].w);
        }
        i += 4;
    }
    for (; i < r1; ++i) {
        ushort4 h = *(const ushort4*)&Hs[(size_t)sorted_src[i] * 256 + c];
        a0 += bf2f(h.x); a1 += bf2f(h.y); a2 += bf2f(h.z); a3 += bf2f(h.w);
    }

    float dv = dinv[node];
    float4 bb = *(const float4*)&bias[c];
    float o0 = fmaxf(bb.x + dv * a0, 0.f);
    float o1 = fmaxf(bb.y + dv * a1, 0.f);
    float o2 = fmaxf(bb.z + dv * a2, 0.f);
    float o3 = fmaxf(bb.w + dv * a3, 0.f);
    *(ushort4*)&outb[(size_t)node * 256 + c] = make_ushort4(f2bf(o0), f2bf(o1), f2bf(o2), f2bf(o3));
}

// layer-2 agg: 2 nodes per wave (32 lanes/node, ushort4 = 8B loads per lane)

__global__ __launch_bounds__(256) void agg_pull_128_bf16(
        const int* __restrict__ rp, const int* __restrict__ sorted_src,
        const float* __restrict__ dinv, const unsigned short* __restrict__ Hs,
        const float* __restrict__ bias, float* __restrict__ out, int N) {
    int node = blockIdx.x * 8 + ((threadIdx.x >> 6) << 1) + ((threadIdx.x >> 5) & 1);
    int l = threadIdx.x & 31;
    if (node >= N) return;

    int r0 = rp[node];
    int r1 = rp[node + 1];
    int c = l << 2;
    ushort4 hv = *(const ushort4*)&Hs[(size_t)node * 128 + c];
    float a0 = bf2f(hv.x), a1 = bf2f(hv.y), a2 = bf2f(hv.z), a3 = bf2f(hv.w);

    int i = r0;
    for (; i + 8 <= r1; i += 8) {
        int s[8];
        #pragma unroll
        for (int u = 0; u < 8; ++u) s[u] = sorted_src[i + u];
        ushort4 h[8];
        #pragma unroll
        for (int u = 0; u < 8; ++u) h[u] = *(const ushort4*)&Hs[(size_t)s[u] * 128 + c];
        #pragma unroll
        for (int u = 0; u < 8; ++u) {
            a0 += bf2f(h[u].x); a1 += bf2f(h[u].y);
            a2 += bf2f(h[u].z); a3 += bf2f(h[u].w);
        }
    }
    if (i + 4 <= r1) {
        int s[4];
        #pragma unroll
        for (int u = 0; u < 4; ++u) s[u] = sorted_src[i + u];
        ushort4 h[4];
        #pragma unroll
        for (int u = 0; u < 4; ++u) h[u] = *(const ushort4*)&Hs[(size_t)s[u] * 128 + c];
        #pragma unroll
        for (int u = 0; u < 4; ++u) {
            a0 += bf2f(h[u].x); a1 += bf2f(h[u].y);
            a2 += bf2f(h[u].z); a3 += bf2f(h[u].w);
        }
        i += 4;
    }
    for (; i < r1; ++i) {
        ushort4 h = *(const ushort4*)&Hs[(size_t)sorted_src[i] * 128 + c];
        a0 += bf2f(h.x); a1 += bf2f(h.y); a2 += bf2f(h.z); a3 += bf2f(h.w);
    }

    float dv = dinv[node];
    float4 bb = *(const float4*)&bias[c];
    float4 o = make_float4(bb.x + dv * a0, bb.y + dv * a1,
                           bb.z + dv * a2, bb.w + dv * a3);
    *(float4*)&out[(size_t)node * 128 + c] = o;
}

// ==================== launch ====================

extern "C" void kernel_launch(void* const* d_in, const int* in_sizes, int n_in,
                              void* d_out, int out_size, void* d_ws, size_t ws_size,
                              hipStream_t stream) {
    const float* x   = (const float*)d_in[0];
    const int*   ei  = (const int*)d_in[1];
    const float* W1  = (const float*)d_in[2];
    const float* b1  = (const float*)d_in[3];
    const float* W2  = (const float*)d_in[4];
    const float* b2  = (const float*)d_in[5];
    float* out       = (float*)d_out;

    const int E   = in_sizes[1] / 2;           // 3,200,000
    const int HID = in_sizes[3];               // 256
    const int IN  = in_sizes[2] / HID;         // 256
    const int OUT = in_sizes[5];               // 128
    const int N   = in_sizes[0] / IN;          // 100,000
    const int span2 = (N + 255) / 256;         // 391 (dst-range per bucket, <=512)
    const int qcap  = E / 256 + 1536;          // bucket capacity w/ ~12-sigma slack

    char* ws = (char*)d_ws;
    int*   row_ptr    = (int*)ws;                                     // (N+1) ints
    int*   deg        = (int*)(ws + (512 << 10));                     // N ints
    float* dinv       = (float*)(ws + (1 << 20));                     // N floats
    int*   block_sums = (int*)(ws + 1572864);                         // ~400 ints
    int*   qcnt       = (int*)(ws + 1638400);                         // 256 ints
    unsigned short* W1t = (unsigned short*)(ws + 1703936);            // 256*256 bf16 (transposed)
    unsigned short* W2t = (unsigned short*)(ws + 1867776);            // 128*256 bf16 (transposed)
    int*   sorted_src = (int*)(ws + (2 << 20));                       // E ints (12.8MB)
    unsigned short* Hsb = (unsigned short*)(ws + ((size_t)16 << 20)); // N*256 bf16 (51.2MB)
    unsigned short* A1b = (unsigned short*)(ws + ((size_t)80 << 20)); // N*256 bf16 (51.2MB)
    int2*  qpair      = (int2*)(ws + ((size_t)136 << 20));            // 256*qcap int2 (~28.5MB)

    const int* e_src = ei;
    const int* e_dst = ei + E;
    const int nb_scan = (N + 255) / 256;

    // ---- CSR build: bin -> hist -> scan -> place (no global atomic ranking) ----
    hipMemsetAsync(qcnt, 0, 256 * sizeof(int), stream);
    partition_edges256<<<(E + 2047) / 2048, 256, 0, stream>>>(e_src, e_dst, qpair, qcnt,
                                                              E, span2, qcap);
    hist_bucket<<<256, 1024, 0, stream>>>(qpair, qcnt, deg, N, span2, qcap);
    scan_blocks<<<nb_scan, 256, 0, stream>>>(deg, row_ptr, block_sums, dinv, N);
    scan_sums<<<1, 512, 0, stream>>>(block_sums, nb_scan);
    scan_add<<<(N + 256) / 256, 256, 0, stream>>>(row_ptr, block_sums, N, E);
    place_bucket<<<256, 1024, 0, stream>>>(qpair, qcnt, row_ptr, sorted_src, N, span2, qcap);

    // ---- weight convert + transpose (one dispatch) ----
    convert_weights_t<<<96, 256, 0, stream>>>(W1, W2, W1t, W2t, IN, HID, OUT);

    // ---- layer 1: Hsb = bf16(dinv * (X@W1)), X read as f32 ----
    gemm_mfma<256, true><<<(N + 127) / 128, 512, 0, stream>>>(x, W1t, Hsb, dinv, N, IN);
    agg_pull_256_bf16<<<(N + 3) / 4, 256, 0, stream>>>(row_ptr, sorted_src, dinv, Hsb, b1, A1b, N);

    // ---- layer 2: Hs2 = bf16(dinv * (A1b@W2)) (reuses Hsb region) ----
    gemm_mfma<128, false><<<(N + 127) / 128, 512, 0, stream>>>(A1b, W2t, Hsb, dinv, N, HID);
    agg_pull_128_bf16<<<(N + 7) / 8, 256, 0, stream>>>(row_ptr, sorted_src, dinv, Hsb, b2, out, N);
}

// Round 14
// 475.348 us; speedup vs baseline: 1.2932x; 1.0218x over previous
//
#include <hip/hip_runtime.h>

using f32x4 = __attribute__((ext_vector_type(4))) float;
using s16x8 = __attribute__((ext_vector_type(8))) short;

static __device__ __forceinline__ unsigned short f2bf(float f) {
    union { float f; unsigned u; } v; v.f = f;
    unsigned r = v.u + 0x7fffu + ((v.u >> 16) & 1u);  // round-to-nearest-even
    return (unsigned short)(r >> 16);
}
static __device__ __forceinline__ float bf2f(unsigned short h) {
    union { unsigned u; float f; } v; v.u = ((unsigned)h) << 16;
    return v.f;
}

// ==================== pass 1: bin edges into 256 dst-range buckets ====================

__global__ __launch_bounds__(256) void partition_edges256(
        const int* __restrict__ src, const int* __restrict__ dst,
        int2* __restrict__ qpair, int* __restrict__ qcnt,
        int E, int span2, int qcap) {
    __shared__ int2 buf[256][32];
    __shared__ int cnt[256];
    const int tid = threadIdx.x;
    cnt[tid] = 0;
    __syncthreads();

    const int e0 = blockIdx.x * 2048;
    const int e1 = min(e0 + 2048, E);
    for (int i = e0 + tid; i < e1; i += 256) {
        int d = dst[i];
        int s = src[i];
        int b = (unsigned)d / (unsigned)span2;
        int p = atomicAdd(&cnt[b], 1);
        if (p < 32) {
            buf[b][p] = make_int2(d, s);
        } else {  // statistically-negligible overflow: direct global append
            int gp = atomicAdd(&qcnt[b], 1);
            qpair[(size_t)b * qcap + gp] = make_int2(d, s);
        }
    }
    __syncthreads();
    int c = min(cnt[tid], 32);
    if (c > 0) {
        int gb = atomicAdd(&qcnt[tid], c);
        int2* q = qpair + (size_t)tid * qcap + gb;
        for (int j = 0; j < c; ++j) q[j] = buf[tid][j];
    }
}

// ==================== pass 2: fused hist + scan + row_ptr/dinv + place ====================
// Block b handles bucket b (nodes [base, base+span2)):
//  1. qbase = sum qcnt[0..b)          (LDS tree reduction)
//  2. LDS histogram of bucket queue
//  3. in-LDS exclusive scan (512-wide) -> row_ptr, dinv
//  4. LDS-cursor placement -> sorted_src (contiguous per-bucket region)

__global__ __launch_bounds__(1024) void csr_bucket(
        const int2* __restrict__ qpair, const int* __restrict__ qcnt,
        int* __restrict__ row_ptr, float* __restrict__ dinv,
        int* __restrict__ sorted_src, int N, int E, int span2, int qcap) {
    __shared__ int red[256];
    __shared__ int h[512];
    const int b = blockIdx.x;
    const int base = b * span2;
    const int tid = threadIdx.x;

    // 1. bucket base offset = sum of qcnt[0..b)
    if (tid < 256) red[tid] = (tid < b) ? qcnt[tid] : 0;
    __syncthreads();
    #pragma unroll
    for (int off = 128; off > 0; off >>= 1) {
        if (tid < off) red[tid] += red[tid + off];
        __syncthreads();
    }
    const int qbase = red[0];
    const int len = qcnt[b];
    const int2* q = qpair + (size_t)b * qcap;

    // 2. LDS histogram
    if (tid < 512) h[tid] = 0;
    __syncthreads();
    for (int i = tid; i < len; i += 1024)
        atomicAdd(&h[q[i].x - base], 1);
    __syncthreads();

    // 3. inclusive scan over 512 (double-barrier Hillis-Steele)
    int deg_t = (tid < 512) ? h[tid] : 0;
    #pragma unroll
    for (int off = 1; off < 512; off <<= 1) {
        int add = (tid >= off && tid < 512) ? h[tid - off] : 0;
        __syncthreads();
        if (tid < 512) h[tid] += add;
        __syncthreads();
    }
    int width = N - base; if (width > span2) width = span2; if (width < 0) width = 0;
    if (tid < width) {
        row_ptr[base + tid] = qbase + h[tid] - deg_t;   // exclusive
        dinv[base + tid] = rsqrtf((float)(deg_t + 1));  // +1 self-loop
    }
    if (b == 255 && tid == 0) row_ptr[N] = E;

    // 4. cursors = exclusive + qbase; place
    if (tid < 512) h[tid] = qbase + h[tid] - deg_t;
    __syncthreads();
    for (int i = tid; i < len; i += 1024) {
        int2 p = q[i];
        int pos = atomicAdd(&h[p.x - base], 1);
        sorted_src[pos] = p.y;
    }
}

// ==================== weight convert + TRANSPOSE (single dispatch) ====================

__global__ void convert_weights_t(const float* __restrict__ W1, const float* __restrict__ W2,
                                  unsigned short* __restrict__ W1t, unsigned short* __restrict__ W2t,
                                  int K, int N1, int N2) {
    int i = blockIdx.x * blockDim.x + threadIdx.x;
    int k4 = K / 4;
    int tot1 = N1 * k4;
    int tot2 = N2 * k4;
    if (i < tot1) {
        int n = i / k4, k0 = (i % k4) * 4;
        ushort4 o = make_ushort4(f2bf(W1[(size_t)(k0 + 0) * N1 + n]),
                                 f2bf(W1[(size_t)(k0 + 1) * N1 + n]),
                                 f2bf(W1[(size_t)(k0 + 2) * N1 + n]),
                                 f2bf(W1[(size_t)(k0 + 3) * N1 + n]));
        *(ushort4*)&W1t[(size_t)n * K + k0] = o;
    } else if (i - tot1 < tot2) {
        int j = i - tot1;
        int n = j / k4, k0 = (j % k4) * 4;
        ushort4 o = make_ushort4(f2bf(W2[(size_t)(k0 + 0) * N2 + n]),
                                 f2bf(W2[(size_t)(k0 + 1) * N2 + n]),
                                 f2bf(W2[(size_t)(k0 + 2) * N2 + n]),
                                 f2bf(W2[(size_t)(k0 + 3) * N2 + n]));
        *(ushort4*)&W2t[(size_t)n * K + k0] = o;
    }
}

// ==================== bf16 MFMA GEMM, 128-row tile, 8 waves, A-prefetch pipeline ====================
// T14 issue-early/write-late: next A tile loaded into regs before this tile's MFMA;
// stored to LDS after the barrier. B loaded direct (weights L2-resident).

template<int BN, bool AF32>
__global__ __launch_bounds__(512, 4) void gemm_mfma(
        const void* __restrict__ Av, const unsigned short* __restrict__ Bt_g,
        unsigned short* __restrict__ C, const float* __restrict__ dinv,
        int M, int K) {
    constexpr int FN = BN / 64;                  // n-fragments per wave (4 or 2)
    __shared__ __align__(16) short As[128][40];  // pad 32->40
    __shared__ __align__(16) short Bt[BN][40];   // [col][k]

    const int tid  = threadIdx.x;
    const int lane = tid & 63;
    const int wave = tid >> 6;                   // 0..7
    const int wm = wave >> 2;                    // row half
    const int wn = wave & 3;                     // col quarter
    const int brow = blockIdx.x * 128;

    const int fr = lane & 15;
    const int kk = (lane >> 4) * 8;

    const int ar = tid >> 2;                     // 0..127
    const int ac = (tid & 3) * 8;                // 0,8,16,24
    const int gr = brow + ar;

    f32x4 acc[4][FN] = {};
    float4 pa0 = make_float4(0.f, 0.f, 0.f, 0.f), pa1 = pa0;
    s16x8 pas = {};

    // prologue: prefetch A tile k0=0
    if (gr < M) {
        if constexpr (AF32) {
            const float* A = (const float*)Av;
            pa0 = *(const float4*)&A[(size_t)gr * K + ac];
            pa1 = *(const float4*)&A[(size_t)gr * K + ac + 4];
        } else {
            const unsigned short* A = (const unsigned short*)Av;
            pas = *(const s16x8*)&A[(size_t)gr * K + ac];
        }
    }

    for (int k0 = 0; k0 < K; k0 += 32) {
        // ---- write prefetched A to LDS (convert here if f32) ----
        {
            s16x8 s;
            if constexpr (AF32) {
                s[0] = (short)f2bf(pa0.x); s[1] = (short)f2bf(pa0.y);
                s[2] = (short)f2bf(pa0.z); s[3] = (short)f2bf(pa0.w);
                s[4] = (short)f2bf(pa1.x); s[5] = (short)f2bf(pa1.y);
                s[6] = (short)f2bf(pa1.z); s[7] = (short)f2bf(pa1.w);
            } else {
                s = pas;
            }
            *(s16x8*)&As[ar][ac] = s;
        }
        // ---- B: direct global->LDS vector copy (L2-hit) ----
        #pragma unroll
        for (int p = 0; p < BN / 128; ++p) {
            int ci = tid + p * 512;
            int col = ci >> 2;
            int kc = (ci & 3) * 8;
            *(s16x8*)&Bt[col][kc] = *(const s16x8*)&Bt_g[(size_t)col * K + k0 + kc];
        }
        __syncthreads();

        // ---- prefetch next A tile (hides under MFMA) ----
        int kn = k0 + 32;
        if (kn < K && gr < M) {
            if constexpr (AF32) {
                const float* A = (const float*)Av;
                pa0 = *(const float4*)&A[(size_t)gr * K + kn + ac];
                pa1 = *(const float4*)&A[(size_t)gr * K + kn + ac + 4];
            } else {
                const unsigned short* A = (const unsigned short*)Av;
                pas = *(const s16x8*)&A[(size_t)gr * K + kn + ac];
            }
        }

        // ---- compute ----
        s16x8 af[4], bv[FN];
        #pragma unroll
        for (int fm = 0; fm < 4; ++fm)
            af[fm] = *(const s16x8*)&As[wm * 64 + fm * 16 + fr][kk];
        #pragma unroll
        for (int fn = 0; fn < FN; ++fn)
            bv[fn] = *(const s16x8*)&Bt[wn * (BN / 4) + fn * 16 + fr][kk];
        #pragma unroll
        for (int fm = 0; fm < 4; ++fm)
            #pragma unroll
            for (int fn = 0; fn < FN; ++fn)
                acc[fm][fn] = __builtin_amdgcn_mfma_f32_16x16x32_bf16(
                    af[fm], bv[fn], acc[fm][fn], 0, 0, 0);
        __syncthreads();
    }

    // C/D layout: col = lane&15, row = (lane>>4)*4 + reg  [m89-verified]
    const int orow = (lane >> 4) * 4;
    #pragma unroll
    for (int fm = 0; fm < 4; ++fm) {
        #pragma unroll
        for (int reg = 0; reg < 4; ++reg) {
            int grr = brow + wm * 64 + fm * 16 + orow + reg;
            if (grr < M) {
                float dv = dinv[grr];
                #pragma unroll
                for (int fn = 0; fn < FN; ++fn) {
                    int gc = wn * (BN / 4) + fn * 16 + fr;
                    C[(size_t)grr * BN + gc] = f2bf(dv * acc[fm][fn][reg]);
                }
            }
        }
    }
}

// ==================== pull aggregation ====================

__global__ __launch_bounds__(256) void agg_pull_256_bf16(
        const int* __restrict__ rp, const int* __restrict__ sorted_src,
        const float* __restrict__ dinv, const unsigned short* __restrict__ Hs,
        const float* __restrict__ bias, unsigned short* __restrict__ outb, int N) {
    int node = blockIdx.x * 4 + (threadIdx.x >> 6);
    int lane = threadIdx.x & 63;
    if (node >= N) return;

    int r0 = rp[node];
    int r1 = rp[node + 1];
    int c = lane << 2;
    ushort4 hv = *(const ushort4*)&Hs[(size_t)node * 256 + c];
    float a0 = bf2f(hv.x), a1 = bf2f(hv.y), a2 = bf2f(hv.z), a3 = bf2f(hv.w);

    int i = r0;
    for (; i + 8 <= r1; i += 8) {
        int s[8];
        #pragma unroll
        for (int u = 0; u < 8; ++u) s[u] = sorted_src[i + u];
        ushort4 h[8];
        #pragma unroll
        for (int u = 0; u < 8; ++u) h[u] = *(const ushort4*)&Hs[(size_t)s[u] * 256 + c];
        #pragma unroll
        for (int u = 0; u < 8; ++u) {
            a0 += bf2f(h[u].x); a1 += bf2f(h[u].y);
            a2 += bf2f(h[u].z); a3 += bf2f(h[u].w);
        }
    }
    if (i + 4 <= r1) {
        int s[4];
        #pragma unroll
        for (int u = 0; u < 4; ++u) s[u] = sorted_src[i + u];
        ushort4 h[4];
        #pragma unroll
        for (int u = 0; u < 4; ++u) h[u] = *(const ushort4*)&Hs[(size_t)s[u] * 256 + c];
        #pragma unroll
        for (int u = 0; u < 4; ++u) {
            a0 += bf2f(h[u].x); a1 += bf2f(h[u].y);
            a2 += bf2f(h[u].z); a3 += bf2f(h[u].w);
        }
        i += 4;
    }
    for (; i < r1; ++i) {
        ushort4 h = *(const ushort4*)&Hs[(size_t)sorted_src[i] * 256 + c];
        a0 += bf2f(h.x); a1 += bf2f(h.y); a2 += bf2f(h.z); a3 += bf2f(h.w);
    }

    float dv = dinv[node];
    float4 bb = *(const float4*)&bias[c];
    float o0 = fmaxf(bb.x + dv * a0, 0.f);
    float o1 = fmaxf(bb.y + dv * a1, 0.f);
    float o2 = fmaxf(bb.z + dv * a2, 0.f);
    float o3 = fmaxf(bb.w + dv * a3, 0.f);
    *(ushort4*)&outb[(size_t)node * 256 + c] = make_ushort4(f2bf(o0), f2bf(o1), f2bf(o2), f2bf(o3));
}

// layer-2 agg: 2 nodes per wave (32 lanes/node, ushort4 = 8B loads per lane)

__global__ __launch_bounds__(256) void agg_pull_128_bf16(
        const int* __restrict__ rp, const int* __restrict__ sorted_src,
        const float* __restrict__ dinv, const unsigned short* __restrict__ Hs,
        const float* __restrict__ bias, float* __restrict__ out, int N) {
    int node = blockIdx.x * 8 + ((threadIdx.x >> 6) << 1) + ((threadIdx.x >> 5) & 1);
    int l = threadIdx.x & 31;
    if (node >= N) return;

    int r0 = rp[node];
    int r1 = rp[node + 1];
    int c = l << 2;
    ushort4 hv = *(const ushort4*)&Hs[(size_t)node * 128 + c];
    float a0 = bf2f(hv.x), a1 = bf2f(hv.y), a2 = bf2f(hv.z), a3 = bf2f(hv.w);

    int i = r0;
    for (; i + 8 <= r1; i += 8) {
        int s[8];
        #pragma unroll
        for (int u = 0; u < 8; ++u) s[u] = sorted_src[i + u];
        ushort4 h[8];
        #pragma unroll
        for (int u = 0; u < 8; ++u) h[u] = *(const ushort4*)&Hs[(size_t)s[u] * 128 + c];
        #pragma unroll
        for (int u = 0; u < 8; ++u) {
            a0 += bf2f(h[u].x); a1 += bf2f(h[u].y);
            a2 += bf2f(h[u].z); a3 += bf2f(h[u].w);
        }
    }
    if (i + 4 <= r1) {
        int s[4];
        #pragma unroll
        for (int u = 0; u < 4; ++u) s[u] = sorted_src[i + u];
        ushort4 h[4];
        #pragma unroll
        for (int u = 0; u < 4; ++u) h[u] = *(const ushort4*)&Hs[(size_t)s[u] * 128 + c];
        #pragma unroll
        for (int u = 0; u < 4; ++u) {
            a0 += bf2f(h[u].x); a1 += bf2f(h[u].y);
            a2 += bf2f(h[u].z); a3 += bf2f(h[u].w);
        }
        i += 4;
    }
    for (; i < r1; ++i) {
        ushort4 h = *(const ushort4*)&Hs[(size_t)sorted_src[i] * 128 + c];
        a0 += bf2f(h.x); a1 += bf2f(h.y); a2 += bf2f(h.z); a3 += bf2f(h.w);
    }

    float dv = dinv[node];
    float4 bb = *(const float4*)&bias[c];
    float4 o = make_float4(bb.x + dv * a0, bb.y + dv * a1,
                           bb.z + dv * a2, bb.w + dv * a3);
    *(float4*)&out[(size_t)node * 128 + c] = o;
}

// ==================== launch ====================

extern "C" void kernel_launch(void* const* d_in, const int* in_sizes, int n_in,
                              void* d_out, int out_size, void* d_ws, size_t ws_size,
                              hipStream_t stream) {
    const float* x   = (const float*)d_in[0];
    const int*   ei  = (const int*)d_in[1];
    const float* W1  = (const float*)d_in[2];
    const float* b1  = (const float*)d_in[3];
    const float* W2  = (const float*)d_in[4];
    const float* b2  = (const float*)d_in[5];
    float* out       = (float*)d_out;

    const int E   = in_sizes[1] / 2;           // 3,200,000
    const int HID = in_sizes[3];               // 256
    const int IN  = in_sizes[2] / HID;         // 256
    const int OUT = in_sizes[5];               // 128
    const int N   = in_sizes[0] / IN;          // 100,000
    const int span2 = (N + 255) / 256;         // 391 (dst-range per bucket, <=512)
    const int qcap  = E / 256 + 1536;          // bucket capacity w/ ~12-sigma slack

    char* ws = (char*)d_ws;
    int*   row_ptr    = (int*)ws;                                     // (N+1) ints
    float* dinv       = (float*)(ws + (1 << 20));                     // N floats
    int*   qcnt       = (int*)(ws + 1638400);                         // 256 ints
    unsigned short* W1t = (unsigned short*)(ws + 1703936);            // 256*256 bf16 (transposed)
    unsigned short* W2t = (unsigned short*)(ws + 1867776);            // 128*256 bf16 (transposed)
    int*   sorted_src = (int*)(ws + (2 << 20));                       // E ints (12.8MB)
    unsigned short* Hsb = (unsigned short*)(ws + ((size_t)16 << 20)); // N*256 bf16 (51.2MB)
    unsigned short* A1b = (unsigned short*)(ws + ((size_t)80 << 20)); // N*256 bf16 (51.2MB)
    int2*  qpair      = (int2*)(ws + ((size_t)136 << 20));            // 256*qcap int2 (~28.5MB)

    const int* e_src = ei;
    const int* e_dst = ei + E;

    // ---- CSR build: bin -> fused(hist+scan+place) ----
    hipMemsetAsync(qcnt, 0, 256 * sizeof(int), stream);
    partition_edges256<<<(E + 2047) / 2048, 256, 0, stream>>>(e_src, e_dst, qpair, qcnt,
                                                              E, span2, qcap);
    csr_bucket<<<256, 1024, 0, stream>>>(qpair, qcnt, row_ptr, dinv, sorted_src,
                                         N, E, span2, qcap);

    // ---- weight convert + transpose (one dispatch) ----
    convert_weights_t<<<96, 256, 0, stream>>>(W1, W2, W1t, W2t, IN, HID, OUT);

    // ---- layer 1: Hsb = bf16(dinv * (X@W1)), X read as f32 ----
    gemm_mfma<256, true><<<(N + 127) / 128, 512, 0, stream>>>(x, W1t, Hsb, dinv, N, IN);
    agg_pull_256_bf16<<<(N + 3) / 4, 256, 0, stream>>>(row_ptr, sorted_src, dinv, Hsb, b1, A1b, N);

    // ---- layer 2: Hs2 = bf16(dinv * (A1b@W2)) (reuses Hsb region) ----
    gemm_mfma<128, false><<<(N + 127) / 128, 512, 0, stream>>>(A1b, W2t, Hsb, dinv, N, HID);
    agg_pull_128_bf16<<<(N + 7) / 8, 256, 0, stream>>>(row_ptr, sorted_src, dinv, Hsb, b2, out, N);
}